// Round 1
// baseline (257.643 us; speedup 1.0000x reference)
//
#include <hip/hip_runtime.h>
#include <hip/hip_bf16.h>
#include <stdint.h>

#define B_   4
#define T_   2048
#define D_   1024
#define H_   16
#define HD_  64
#define MROWS (B_*T_)      // 8192
#define NQKV  3072
#define NST  (T_/64)       // 32 s-tiles per head

typedef __attribute__((ext_vector_type(8))) short  short8;   // 8 x bf16
typedef __attribute__((ext_vector_type(4))) short  bf16x4;   // 4 x bf16 (avoid HIP's short4)
typedef __attribute__((ext_vector_type(4))) float  floatx4;

#define QSCALE 0.1803368801111244f   // log2(e)/sqrt(64)

__device__ inline void async_copy16(const __hip_bfloat16* g, __hip_bfloat16* l) {
  __builtin_amdgcn_global_load_lds(
      (const __attribute__((address_space(1))) void*)g,
      (__attribute__((address_space(3))) void*)l, 16, 0, 0);
}

// K=16 bf16 MFMA (gfx950: ..._16x16x16bf16_1k; fallback keeps it compiling)
__device__ inline floatx4 mfma16(bf16x4 a, bf16x4 b, floatx4 c) {
#if __has_builtin(__builtin_amdgcn_mfma_f32_16x16x16bf16_1k)
  return __builtin_amdgcn_mfma_f32_16x16x16bf16_1k(a, b, c, 0, 0, 0);
#elif __has_builtin(__builtin_amdgcn_mfma_f32_16x16x16_bf16)
  return __builtin_amdgcn_mfma_f32_16x16x16_bf16(a, b, c, 0, 0, 0);
#else
  short8 a8 = (short8){a[0], a[1], a[2], a[3], 0, 0, 0, 0};
  short8 b8 = (short8){b[0], b[1], b[2], b[3], 0, 0, 0, 0};
  return __builtin_amdgcn_mfma_f32_16x16x32_bf16(a8, b8, c, 0, 0, 0);
#endif
}

// ---------------- conversion kernels ----------------

__global__ void convert_bf16(const float* __restrict__ in, __hip_bfloat16* __restrict__ out, int n) {
  int i = (blockIdx.x * blockDim.x + threadIdx.x) * 4;
  if (i < n) {
    float4 v = *(const float4*)(in + i);
    out[i + 0] = __float2bfloat16(v.x);
    out[i + 1] = __float2bfloat16(v.y);
    out[i + 2] = __float2bfloat16(v.z);
    out[i + 3] = __float2bfloat16(v.w);
  }
}

__global__ void transpose_w(const float* __restrict__ Wq, const float* __restrict__ Wk,
                            const float* __restrict__ Wv, __hip_bfloat16* __restrict__ wqkv) {
  __shared__ __hip_bfloat16 tile[64][65];
  const int t = threadIdx.x;
  const int d0 = blockIdx.x * 64;
  const int wh = blockIdx.y;           // 0..47
  const int which = wh >> 4, h = wh & 15;
  const float* W = (which == 0) ? Wq : ((which == 1) ? Wk : Wv);
  const float* base = W + (size_t)h * D_ * HD_;
#pragma unroll
  for (int i = 0; i < 16; i++) {
    int e = i * 256 + t;
    int dr = e >> 6, hd = e & 63;
    tile[dr][hd] = __float2bfloat16(base[(size_t)(d0 + dr) * HD_ + hd]);
  }
  __syncthreads();
#pragma unroll
  for (int i = 0; i < 16; i++) {
    int e = i * 256 + t;
    int hd = e >> 6, dr = e & 63;
    wqkv[(size_t)(which * 1024 + h * 64 + hd) * D_ + d0 + dr] = tile[dr][hd];
  }
}

// ---------------- repack K,V into fragment-contiguous tiles ----------------
__global__ void repack_kv(const __hip_bfloat16* __restrict__ qkv,
                          __hip_bfloat16* __restrict__ kpack, __hip_bfloat16* __restrict__ vpack) {
  __shared__ __hip_bfloat16 Ks[64][72];
  __shared__ __hip_bfloat16 Vs[64][72];
  const int tid = threadIdx.x;
  const int st = blockIdx.x, bh = blockIdx.y;
  const int b = bh >> 4, h = bh & 15;
#pragma unroll
  for (int p = 0; p < 2; p++) {
    int c = p * 256 + tid;           // 512 chunks of 16B per matrix
    int row = c >> 3, col8 = c & 7;
    const __hip_bfloat16* src = qkv + (size_t)(b * T_ + st * 64 + row) * NQKV + h * HD_ + col8 * 8;
    *(uint4*)&Ks[row][col8 * 8] = *(const uint4*)(src + 1024);
    *(uint4*)&Vs[row][col8 * 8] = *(const uint4*)(src + 2048);
  }
  __syncthreads();
  const size_t base = ((size_t)bh * NST + st) * 8 * 512;
#pragma unroll
  for (int p = 0; p < 2; p++) {
    int pair = p * 256 + tid;        // 8 chunks x 64 lanes
    int c = pair >> 6, l = pair & 63;
    int lq = l & 15, q = l >> 4;
    int ni = c >> 1, half = c & 1;
    short8 v = *(const short8*)&Ks[ni * 16 + lq][half * 32 + q * 8];
    *(short8*)(kpack + base + (size_t)c * 512 + l * 8) = v;
  }
#pragma unroll
  for (int p = 0; p < 2; p++) {
    int pair = p * 256 + tid;
    int c = pair >> 6, l = pair & 63;
    int lq = l & 15, q = l >> 4;
    int m = c >> 2, nt = c & 3;
    __hip_bfloat16 tmp[8];
#pragma unroll
    for (int half = 0; half < 2; half++)
#pragma unroll
      for (int j = 0; j < 4; j++)
        tmp[half * 4 + j] = Vs[(2 * m + half) * 16 + q * 4 + j][nt * 16 + lq];
    *(short8*)(vpack + base + (size_t)c * 512 + l * 8) = *(short8*)tmp;
  }
}

// ---------------- 256x256 8-phase GEMM (QKV projection): C = A[M,K] * Bt[N,K]^T ----------------
// T2: row-XOR LDS swizzle (byte ^= (row&7)<<4), applied to global SOURCE of
//     global_load_lds (LDS dest stays linear, rule 21) and to ds_read addresses.
// T3+T4: 4 phases per K-tile (quadrants Q00,Q01,Q11,Q10), 1 half-tile staged per
//     phase, counted s_waitcnt vmcnt(4) only at the tile boundary (2 half-tiles of
//     tile t+2 stay in flight across the barrier). T5: setprio around MFMA cluster.
// Liveness: B-halves of buf last read at P1, A-halves at P2 -> staging tile t+2's
//     B0 at P2 and A0 at P3 into the CURRENT buffer is race-free (barrier-ordered).

__device__ inline void stage_half(const __hip_bfloat16* __restrict__ gsrc, int ldk,
                                  short* ldst, int tid) {
  // half-tile = 128 rows x 64 cols bf16 = 16 KB = 512 thr x 2 x 16B
#pragma unroll
  for (int l = 0; l < 2; ++l) {
    int c = l * 512 + tid;                     // chunk 0..1023
    int row = c >> 3;                          // 0..127
    int sce = ((((c & 7) << 4) ^ ((row & 7) << 4)) >> 1);   // swizzled elem col
    async_copy16(gsrc + (size_t)row * ldk + sce, (__hip_bfloat16*)(ldst + c * 8));
  }
}

__device__ inline short8 fragld(const short* base, int row, int kk, int quad) {
  int c2 = ((kk << 6) | (quad << 4)) ^ ((row & 7) << 4);    // swizzled byte col
  return *(const short8*)(base + row * 64 + (c2 >> 1));
}

#define LOAD_A(MQ) \
  _Pragma("unroll") for (int mi = 0; mi < 4; ++mi) \
  _Pragma("unroll") for (int kk = 0; kk < 2; ++kk) \
    a[mi][kk] = fragld(Ab, wr * 128 + (MQ) * 64 + mi * 16 + lq, kk, quad);

#define LOAD_B(DST, NQ) \
  _Pragma("unroll") for (int ni = 0; ni < 2; ++ni) \
  _Pragma("unroll") for (int kk = 0; kk < 2; ++kk) \
    DST[ni][kk] = fragld(Bb, wc * 64 + (NQ) * 32 + ni * 16 + lq, kk, quad);

#define QUAD_MFMA(M0, N0, BREG) \
  _Pragma("unroll") for (int kk = 0; kk < 2; ++kk) \
  _Pragma("unroll") for (int mi = 0; mi < 4; ++mi) \
  _Pragma("unroll") for (int ni = 0; ni < 2; ++ni) \
    acc[(M0) + mi][(N0) + ni] = __builtin_amdgcn_mfma_f32_16x16x32_bf16( \
        a[mi][kk], BREG[ni][kk], acc[(M0) + mi][(N0) + ni], 0, 0, 0);

#define PH_SYNC_BEGIN() \
  __builtin_amdgcn_s_barrier(); \
  asm volatile("s_waitcnt lgkmcnt(0)" ::: "memory"); \
  __builtin_amdgcn_s_setprio(1);

#define PH_SYNC_END() \
  __builtin_amdgcn_s_setprio(0); \
  __builtin_amdgcn_s_barrier();

__launch_bounds__(512, 2)
__global__ void gemm8(const __hip_bfloat16* __restrict__ A, const __hip_bfloat16* __restrict__ Bt,
                      __hip_bfloat16* __restrict__ Cb, int M, int N, int K, float qscale) {
  __shared__ short As[2][16384];   // 2 x [256 rows][64 cols] bf16, 64 KB
  __shared__ short Bs[2][16384];   // 64 KB
  const int tid = threadIdx.x;
  const int lane = tid & 63, wid = tid >> 6;
  const int lq = lane & 15, quad = lane >> 4;
  const int wr = wid >> 2, wc = wid & 3;       // 2 x 4 waves, wave tile 128x64

  // XCD-aware bijective swizzle on linear block id (nwg % 8 == 0 here)
  const int nbx = gridDim.x, nwg = gridDim.x * gridDim.y;
  int lin = blockIdx.y * nbx + blockIdx.x;
  int s = (nwg & 7) ? lin : ((lin & 7) * (nwg >> 3) + (lin >> 3));
  const int m0 = (s % nbx) * 256, n0 = (s / nbx) * 256;

  const int NT = K >> 6;

  // prologue: tile0 {B0,A0,A1,B1} + tile1 {B0,A0}; allow tile1 halves in flight
  stage_half(Bt + (size_t)n0 * K, K, &Bs[0][0], tid);
  stage_half(A + (size_t)m0 * K, K, &As[0][0], tid);
  stage_half(A + (size_t)(m0 + 128) * K, K, &As[0][8192], tid);
  stage_half(Bt + (size_t)(n0 + 128) * K, K, &Bs[0][8192], tid);
  stage_half(Bt + (size_t)n0 * K + 64, K, &Bs[1][0], tid);
  stage_half(A + (size_t)m0 * K + 64, K, &As[1][0], tid);

  floatx4 acc[8][4];
#pragma unroll
  for (int i = 0; i < 8; i++)
#pragma unroll
    for (int j = 0; j < 4; j++) acc[i][j] = (floatx4){0.f, 0.f, 0.f, 0.f};

  asm volatile("s_waitcnt vmcnt(4)" ::: "memory");
  __builtin_amdgcn_s_barrier();

  for (int t = 0; t < NT; ++t) {
    const int buf = t & 1, nbuf = buf ^ 1;
    const short* Ab = As[buf];
    const short* Bb = Bs[buf];
    const int kc1 = (t + 1) << 6, kc2 = (t + 2) << 6;
    short8 a[4][2], b0[2][2], b1[2][2];

    // ---- P0: Q(0,0) ---- stage t+1.A1 (other buffer)
    LOAD_A(0);
    LOAD_B(b0, 0);
    if (t + 1 < NT) stage_half(A + (size_t)(m0 + 128) * K + kc1, K, &As[nbuf][8192], tid);
    PH_SYNC_BEGIN();
    QUAD_MFMA(0, 0, b0);
    PH_SYNC_END();

    // ---- P1: Q(0,1) ---- stage t+1.B1 (other buffer)
    LOAD_B(b1, 1);
    if (t + 1 < NT) stage_half(Bt + (size_t)(n0 + 128) * K + kc1, K, &Bs[nbuf][8192], tid);
    PH_SYNC_BEGIN();
    QUAD_MFMA(0, 2, b1);
    PH_SYNC_END();

    // ---- P2: Q(1,1) ---- stage t+2.B0 into CURRENT buf (B0 dead after P1)
    LOAD_A(1);
    if (t + 2 < NT) stage_half(Bt + (size_t)n0 * K + kc2, K, &Bs[buf][0], tid);
    PH_SYNC_BEGIN();
    QUAD_MFMA(4, 2, b1);
    PH_SYNC_END();

    // ---- P3: Q(1,0) ---- stage t+2.A0 into CURRENT buf (A0 dead after P2)
    if (t + 2 < NT) stage_half(A + (size_t)m0 * K + kc2, K, &As[buf][0], tid);
    __builtin_amdgcn_s_barrier();
    asm volatile("s_waitcnt lgkmcnt(0)" ::: "memory");
    __builtin_amdgcn_s_setprio(1);
    QUAD_MFMA(4, 0, b0);
    __builtin_amdgcn_s_setprio(0);
    // boundary: tile t+1 fully landed; only tile t+2's B0/A0 (4 loads) in flight
    if (t + 2 < NT) { asm volatile("s_waitcnt vmcnt(4)" ::: "memory"); }
    else            { asm volatile("s_waitcnt vmcnt(0)" ::: "memory"); }
    __builtin_amdgcn_s_barrier();
  }

  // epilogue: bf16 store, q-columns pre-scaled by log2e/sqrt(64)
#pragma unroll
  for (int mi = 0; mi < 8; ++mi) {
#pragma unroll
    for (int ni = 0; ni < 4; ++ni) {
      int col = n0 + wc * 64 + ni * 16 + lq;
      float sc = (col < 1024) ? qscale : 1.0f;
#pragma unroll
      for (int r = 0; r < 4; ++r) {
        int row = m0 + wr * 128 + mi * 16 + quad * 4 + r;
        Cb[(size_t)row * N + col] = __float2bfloat16(acc[mi][ni][r] * sc);
      }
    }
  }
}

// ---------------- GEMM: C = A[M,K] * Bt[N,K]^T (kept for output projection) ----------------
template <int EPI>
__launch_bounds__(256, 2)
__global__ void gemm_bt(const __hip_bfloat16* __restrict__ A, const __hip_bfloat16* __restrict__ Bt,
                        __hip_bfloat16* __restrict__ Cb, float* __restrict__ Cf,
                        const float* __restrict__ bias, int M, int N, int K, float qscale) {
  __shared__ __hip_bfloat16 As[128 * 32];
  __shared__ __hip_bfloat16 Bs[128 * 32];
  const int tid = threadIdx.x;
  const int w = tid >> 6, lane = tid & 63;
  const int lq = lane & 15, quad = lane >> 4;
  const int wr = w >> 1, wc = w & 1;
  const int m0 = blockIdx.x * 128, n0 = blockIdx.y * 128;

  floatx4 acc[4][4];
#pragma unroll
  for (int i = 0; i < 4; i++)
#pragma unroll
    for (int j = 0; j < 4; j++) acc[i][j] = (floatx4){0.f, 0.f, 0.f, 0.f};

  for (int k0 = 0; k0 < K; k0 += 32) {
    __syncthreads();
#pragma unroll
    for (int ph = 0; ph < 2; ++ph) {
      int c = ph * 256 + tid;
      int row = c >> 2, col8 = c & 3;
      async_copy16(A + (size_t)(m0 + row) * K + k0 + col8 * 8, As + c * 8);
      async_copy16(Bt + (size_t)(n0 + row) * K + k0 + col8 * 8, Bs + c * 8);
    }
    __syncthreads();
    short8 af[4], bf[4];
#pragma unroll
    for (int mi = 0; mi < 4; mi++)
      af[mi] = *(const short8*)(As + (wr * 64 + mi * 16 + lq) * 32 + quad * 8);
#pragma unroll
    for (int ni = 0; ni < 4; ni++)
      bf[ni] = *(const short8*)(Bs + (wc * 64 + ni * 16 + lq) * 32 + quad * 8);
#pragma unroll
    for (int mi = 0; mi < 4; mi++)
#pragma unroll
      for (int ni = 0; ni < 4; ni++)
        acc[mi][ni] = __builtin_amdgcn_mfma_f32_16x16x32_bf16(af[mi], bf[ni], acc[mi][ni], 0, 0, 0);
  }

#pragma unroll
  for (int mi = 0; mi < 4; mi++) {
#pragma unroll
    for (int ni = 0; ni < 4; ni++) {
      int col = n0 + wc * 64 + ni * 16 + lq;
      if (EPI == 0) {
        float s = (col < 1024) ? qscale : 1.0f;
#pragma unroll
        for (int r = 0; r < 4; r++) {
          int row = m0 + wr * 64 + mi * 16 + quad * 4 + r;
          Cb[(size_t)row * N + col] = __float2bfloat16(acc[mi][ni][r] * s);
        }
      } else {
        float bv = bias[col];
#pragma unroll
        for (int r = 0; r < 4; r++) {
          int row = m0 + wr * 64 + mi * 16 + quad * 4 + r;
          Cf[(size_t)row * N + col] = acc[mi][ni][r] + bv;
        }
      }
    }
  }
}

// ---------------- flash attention: 2 bands/wave, balanced segments, XCD-local ----------------
// Block (bh, a): seg0 = tiles (2a, 2a+1), seg1 = tiles (30-2a, 31-2a).
// Max iters/block = (2a+2)+(32-2a) = 34 uniform -> zero tail; 512 blocks all
// co-resident at 2 blocks/CU. grid(64,8): linear%8 = bh%8 -> one bh per XCD L2.
__launch_bounds__(256, 2)
__global__ void attn(const __hip_bfloat16* __restrict__ qkv,
                     const __hip_bfloat16* __restrict__ kpack,
                     const __hip_bfloat16* __restrict__ vpack,
                     __hip_bfloat16* __restrict__ obuf) {
  const int tid = threadIdx.x;
  const int w = tid >> 6, lane = tid & 63;
  const int lq = lane & 15, quad = lane >> 4;

  const int bh = (int)blockIdx.x;            // XCD = bh % 8
  const int a  = (int)blockIdx.y;            // 0..7
  const int b = bh >> 4, h = bh & 15;

  const __hip_bfloat16* kb0 = kpack + ((size_t)bh * NST) * 4096 + lane * 8;
  const __hip_bfloat16* vb0 = vpack + ((size_t)bh * NST) * 4096 + lane * 8;

#pragma unroll 1
  for (int seg = 0; seg < 2; ++seg) {
    const int tbase = seg ? (NST - 2 - 2 * a) : (2 * a);
    const int qt = tbase + (w >> 1);         // this wave's q-tile
    const int rbase = (w & 1) * 32;          // row base within tile

    // Q fragments for 2 bands: B-operand B[n=lq -> t][k=quad*8+j]
    short8 qf[2][2];
#pragma unroll
    for (int bi = 0; bi < 2; bi++) {
      const __hip_bfloat16* qp =
          qkv + ((size_t)(b * T_ + qt * 64 + rbase + bi * 16 + lq)) * NQKV + h * HD_;
      qf[bi][0] = *(const short8*)(qp + quad * 8);
      qf[bi][1] = *(const short8*)(qp + 32 + quad * 8);
    }

    floatx4 Oacc[2][4];
#pragma unroll
    for (int bi = 0; bi < 2; bi++)
#pragma unroll
      for (int i = 0; i < 4; i++) Oacc[bi][i] = (floatx4){0.f, 0.f, 0.f, 0.f};
    float lrow[2] = {0.f, 0.f};

    const __hip_bfloat16* kb = kb0;
    const __hip_bfloat16* vb = vb0;
    const int nIter = qt + 1;                // wave loops to its own diagonal
    for (int it = 0; it < nIter; ++it) {
      short8 kf[4], kg[4];
#pragma unroll
      for (int ni = 0; ni < 4; ni++) {
        kf[ni] = *(const short8*)(kb + (size_t)(ni * 2 + 0) * 512);
        kg[ni] = *(const short8*)(kb + (size_t)(ni * 2 + 1) * 512);
      }
      short8 vfr[8];
#pragma unroll
      for (int c = 0; c < 8; c++) vfr[c] = *(const short8*)(vb + (size_t)c * 512);

      // S^T = K Q^T for both bands (exp2 domain)
      floatx4 Sc[2][4];
#pragma unroll
      for (int bi = 0; bi < 2; bi++)
#pragma unroll
        for (int ni = 0; ni < 4; ni++) {
          floatx4 c0 = (floatx4){0.f, 0.f, 0.f, 0.f};
          c0 = __builtin_amdgcn_mfma_f32_16x16x32_bf16(kf[ni], qf[bi][0], c0, 0, 0, 0);
          c0 = __builtin_amdgcn_mfma_f32_16x16x32_bf16(kg[ni], qf[bi][1], c0, 0, 0, 0);
          Sc[bi][ni] = c0;   // reg r: s = ni*16 + quad*4 + r, t = lq (band bi)
        }

      // causal mask on the wave's diagonal tile
      if (it == nIter - 1) {
#pragma unroll
        for (int bi = 0; bi < 2; bi++) {
          int lrow_idx = rbase + bi * 16 + lq;
#pragma unroll
          for (int ni = 0; ni < 4; ni++)
#pragma unroll
            for (int r = 0; r < 4; r++) {
              int s_loc = ni * 16 + quad * 4 + r;
              if (s_loc > lrow_idx) Sc[bi][ni][r] = -__builtin_inff();
            }
        }
      }

      // p = exp2(S); per-lane row sums; pack to PV A-frags
      bf16x4 pf[2][4];
#pragma unroll
      for (int bi = 0; bi < 2; bi++)
#pragma unroll
        for (int c = 0; c < 4; c++) {
          __hip_bfloat16 pb[4];
#pragma unroll
          for (int r = 0; r < 4; r++) {
            float p = __builtin_amdgcn_exp2f(Sc[bi][c][r]);
            lrow[bi] += p;
            pb[r] = __float2bfloat16(p);
          }
          pf[bi][c] = *(bf16x4*)pb;
        }

      // O += P V  (both bands share the V fragments)
#pragma unroll
      for (int m = 0; m < 2; m++)
#pragma unroll
        for (int nt = 0; nt < 4; nt++) {
          short8 v8 = vfr[m * 4 + nt];
          bf16x4 vlo = (bf16x4){v8[0], v8[1], v8[2], v8[3]};
          bf16x4 vhi = (bf16x4){v8[4], v8[5], v8[6], v8[7]};
#pragma unroll
          for (int bi = 0; bi < 2; bi++) {
            Oacc[bi][nt] = mfma16(pf[bi][2 * m + 0], vlo, Oacc[bi][nt]);
            Oacc[bi][nt] = mfma16(pf[bi][2 * m + 1], vhi, Oacc[bi][nt]);
          }
        }

      kb += 4096;
      vb += 4096;
    }

    // epilogue per band: reduce lrow across quads, normalize, store
#pragma unroll
    for (int bi = 0; bi < 2; bi++) {
      float ps = lrow[bi];
      ps += __shfl_xor(ps, 16);
      ps += __shfl_xor(ps, 32);
      float inv = 1.0f / ps;                    // valid for t = lq in every lane
#pragma unroll
      for (int r = 0; r < 4; r++) {
        float invr = __shfl(inv, quad * 4 + r); // inv for t = quad*4+r
        int t = qt * 64 + rbase + bi * 16 + quad * 4 + r;
#pragma unroll
        for (int nt = 0; nt < 4; nt++)
          obuf[(size_t)(b * T_ + t) * D_ + h * HD_ + nt * 16 + lq] =
              __float2bfloat16(Oacc[bi][nt][r] * invr);
      }
    }
  }
}

// ---------------- launch ----------------

extern "C" void kernel_launch(void* const* d_in, const int* in_sizes, int n_in,
                              void* d_out, int out_size, void* d_ws, size_t ws_size,
                              hipStream_t stream) {
  const float* x  = (const float*)d_in[0];
  const float* Wq = (const float*)d_in[1];
  const float* Wk = (const float*)d_in[2];
  const float* Wv = (const float*)d_in[3];
  const float* Wo = (const float*)d_in[4];
  const float* bo = (const float*)d_in[5];
  float* out = (float*)d_out;

  char* ws = (char*)d_ws;
  __hip_bfloat16* xb    = (__hip_bfloat16*)(ws);                          // 16 MB (dead after QKV gemm)
  __hip_bfloat16* obuf  = (__hip_bfloat16*)(ws);                          // reuses xb's slot
  __hip_bfloat16* wqkv  = (__hip_bfloat16*)(ws + ((size_t)16 << 20));     //  6 MB
  __hip_bfloat16* wob   = (__hip_bfloat16*)(ws + ((size_t)22 << 20));     //  2 MB
  __hip_bfloat16* qkv   = (__hip_bfloat16*)(ws + ((size_t)24 << 20));     // 48 MB
  __hip_bfloat16* kpack = (__hip_bfloat16*)(ws + ((size_t)72 << 20));     // 16 MB
  __hip_bfloat16* vpack = (__hip_bfloat16*)(ws + ((size_t)88 << 20));     // 16 MB

  convert_bf16<<<(MROWS * D_) / 1024, 256, 0, stream>>>(x, xb, MROWS * D_);
  convert_bf16<<<(D_ * D_) / 1024, 256, 0, stream>>>(Wo, wob, D_ * D_);
  transpose_w<<<dim3(16, 48), 256, 0, stream>>>(Wq, Wk, Wv, wqkv);

  // qkv = xb * wqkv^T   (q columns pre-scaled by log2e/8) — 256² 8-phase kernel
  gemm8<<<dim3(MROWS / 256, NQKV / 256), 512, 0, stream>>>(
      xb, wqkv, qkv, MROWS, NQKV, D_, QSCALE);

  repack_kv<<<dim3(NST, B_ * H_), 256, 0, stream>>>(qkv, kpack, vpack);

  attn<<<dim3(B_ * H_, 8), 256, 0, stream>>>(qkv, kpack, vpack, obuf);

  // out = obuf * Wo^T + bo
  gemm_bt<1><<<dim3(MROWS / 128, D_ / 128), 256, 0, stream>>>(
      obuf, wob, nullptr, out, bo, MROWS, D_, D_, 1.0f);
}

// Round 2
// 251.080 us; speedup vs baseline: 1.0261x; 1.0261x over previous
//
#include <hip/hip_runtime.h>
#include <hip/hip_bf16.h>
#include <stdint.h>

#define B_   4
#define T_   2048
#define D_   1024
#define H_   16
#define HD_  64
#define MROWS (B_*T_)      // 8192
#define NQKV  3072
#define NST  (T_/64)       // 32 s-tiles per head

typedef __attribute__((ext_vector_type(8))) short  short8;   // 8 x bf16
typedef __attribute__((ext_vector_type(4))) short  bf16x4;   // 4 x bf16 (avoid HIP's short4)
typedef __attribute__((ext_vector_type(4))) float  floatx4;

#define QSCALE 0.1803368801111244f   // log2(e)/sqrt(64)

__device__ inline void async_copy16(const __hip_bfloat16* g, __hip_bfloat16* l) {
  __builtin_amdgcn_global_load_lds(
      (const __attribute__((address_space(1))) void*)g,
      (__attribute__((address_space(3))) void*)l, 16, 0, 0);
}

// K=16 bf16 MFMA (gfx950: ..._16x16x16bf16_1k; fallback keeps it compiling)
__device__ inline floatx4 mfma16(bf16x4 a, bf16x4 b, floatx4 c) {
#if __has_builtin(__builtin_amdgcn_mfma_f32_16x16x16bf16_1k)
  return __builtin_amdgcn_mfma_f32_16x16x16bf16_1k(a, b, c, 0, 0, 0);
#elif __has_builtin(__builtin_amdgcn_mfma_f32_16x16x16_bf16)
  return __builtin_amdgcn_mfma_f32_16x16x16_bf16(a, b, c, 0, 0, 0);
#else
  short8 a8 = (short8){a[0], a[1], a[2], a[3], 0, 0, 0, 0};
  short8 b8 = (short8){b[0], b[1], b[2], b[3], 0, 0, 0, 0};
  return __builtin_amdgcn_mfma_f32_16x16x32_bf16(a8, b8, c, 0, 0, 0);
#endif
}

// ---------------- conversion kernels ----------------

__global__ void convert_bf16(const float* __restrict__ in, __hip_bfloat16* __restrict__ out, int n) {
  int i = (blockIdx.x * blockDim.x + threadIdx.x) * 4;
  if (i < n) {
    float4 v = *(const float4*)(in + i);
    out[i + 0] = __float2bfloat16(v.x);
    out[i + 1] = __float2bfloat16(v.y);
    out[i + 2] = __float2bfloat16(v.z);
    out[i + 3] = __float2bfloat16(v.w);
  }
}

__global__ void transpose_w(const float* __restrict__ Wq, const float* __restrict__ Wk,
                            const float* __restrict__ Wv, __hip_bfloat16* __restrict__ wqkv) {
  __shared__ __hip_bfloat16 tile[64][65];
  const int t = threadIdx.x;
  const int d0 = blockIdx.x * 64;
  const int wh = blockIdx.y;           // 0..47
  const int which = wh >> 4, h = wh & 15;
  const float* W = (which == 0) ? Wq : ((which == 1) ? Wk : Wv);
  const float* base = W + (size_t)h * D_ * HD_;
#pragma unroll
  for (int i = 0; i < 16; i++) {
    int e = i * 256 + t;
    int dr = e >> 6, hd = e & 63;
    tile[dr][hd] = __float2bfloat16(base[(size_t)(d0 + dr) * HD_ + hd]);
  }
  __syncthreads();
#pragma unroll
  for (int i = 0; i < 16; i++) {
    int e = i * 256 + t;
    int hd = e >> 6, dr = e & 63;
    wqkv[(size_t)(which * 1024 + h * 64 + hd) * D_ + d0 + dr] = tile[dr][hd];
  }
}

// ---------------- repack K,V into fragment-contiguous tiles ----------------
__global__ void repack_kv(const __hip_bfloat16* __restrict__ qkv,
                          __hip_bfloat16* __restrict__ kpack, __hip_bfloat16* __restrict__ vpack) {
  __shared__ __hip_bfloat16 Ks[64][72];
  __shared__ __hip_bfloat16 Vs[64][72];
  const int tid = threadIdx.x;
  const int st = blockIdx.x, bh = blockIdx.y;
  const int b = bh >> 4, h = bh & 15;
#pragma unroll
  for (int p = 0; p < 2; p++) {
    int c = p * 256 + tid;           // 512 chunks of 16B per matrix
    int row = c >> 3, col8 = c & 7;
    const __hip_bfloat16* src = qkv + (size_t)(b * T_ + st * 64 + row) * NQKV + h * HD_ + col8 * 8;
    *(uint4*)&Ks[row][col8 * 8] = *(const uint4*)(src + 1024);
    *(uint4*)&Vs[row][col8 * 8] = *(const uint4*)(src + 2048);
  }
  __syncthreads();
  const size_t base = ((size_t)bh * NST + st) * 8 * 512;
#pragma unroll
  for (int p = 0; p < 2; p++) {
    int pair = p * 256 + tid;        // 8 chunks x 64 lanes
    int c = pair >> 6, l = pair & 63;
    int lq = l & 15, q = l >> 4;
    int ni = c >> 1, half = c & 1;
    short8 v = *(const short8*)&Ks[ni * 16 + lq][half * 32 + q * 8];
    *(short8*)(kpack + base + (size_t)c * 512 + l * 8) = v;
  }
#pragma unroll
  for (int p = 0; p < 2; p++) {
    int pair = p * 256 + tid;
    int c = pair >> 6, l = pair & 63;
    int lq = l & 15, q = l >> 4;
    int m = c >> 2, nt = c & 3;
    __hip_bfloat16 tmp[8];
#pragma unroll
    for (int half = 0; half < 2; half++)
#pragma unroll
      for (int j = 0; j < 4; j++)
        tmp[half * 4 + j] = Vs[(2 * m + half) * 16 + q * 4 + j][nt * 16 + lq];
    *(short8*)(vpack + base + (size_t)c * 512 + l * 8) = *(short8*)tmp;
  }
}

// ---------------- GEMM: C = A[M,K] * Bt[N,K]^T ----------------
template <int EPI>
__launch_bounds__(256, 2)
__global__ void gemm_bt(const __hip_bfloat16* __restrict__ A, const __hip_bfloat16* __restrict__ Bt,
                        __hip_bfloat16* __restrict__ Cb, float* __restrict__ Cf,
                        const float* __restrict__ bias, int M, int N, int K, float qscale) {
  __shared__ __hip_bfloat16 As[128 * 32];
  __shared__ __hip_bfloat16 Bs[128 * 32];
  const int tid = threadIdx.x;
  const int w = tid >> 6, lane = tid & 63;
  const int lq = lane & 15, quad = lane >> 4;
  const int wr = w >> 1, wc = w & 1;
  const int m0 = blockIdx.x * 128, n0 = blockIdx.y * 128;

  floatx4 acc[4][4];
#pragma unroll
  for (int i = 0; i < 4; i++)
#pragma unroll
    for (int j = 0; j < 4; j++) acc[i][j] = (floatx4){0.f, 0.f, 0.f, 0.f};

  for (int k0 = 0; k0 < K; k0 += 32) {
    __syncthreads();
#pragma unroll
    for (int ph = 0; ph < 2; ++ph) {
      int c = ph * 256 + tid;
      int row = c >> 2, col8 = c & 3;
      async_copy16(A + (size_t)(m0 + row) * K + k0 + col8 * 8, As + c * 8);
      async_copy16(Bt + (size_t)(n0 + row) * K + k0 + col8 * 8, Bs + c * 8);
    }
    __syncthreads();
    short8 af[4], bf[4];
#pragma unroll
    for (int mi = 0; mi < 4; mi++)
      af[mi] = *(const short8*)(As + (wr * 64 + mi * 16 + lq) * 32 + quad * 8);
#pragma unroll
    for (int ni = 0; ni < 4; ni++)
      bf[ni] = *(const short8*)(Bs + (wc * 64 + ni * 16 + lq) * 32 + quad * 8);
#pragma unroll
    for (int mi = 0; mi < 4; mi++)
#pragma unroll
      for (int ni = 0; ni < 4; ni++)
        acc[mi][ni] = __builtin_amdgcn_mfma_f32_16x16x32_bf16(af[mi], bf[ni], acc[mi][ni], 0, 0, 0);
  }

#pragma unroll
  for (int mi = 0; mi < 4; mi++) {
#pragma unroll
    for (int ni = 0; ni < 4; ni++) {
      int col = n0 + wc * 64 + ni * 16 + lq;
      if (EPI == 0) {
        float s = (col < 1024) ? qscale : 1.0f;
#pragma unroll
        for (int r = 0; r < 4; r++) {
          int row = m0 + wr * 64 + mi * 16 + quad * 4 + r;
          Cb[(size_t)row * N + col] = __float2bfloat16(acc[mi][ni][r] * s);
        }
      } else {
        float bv = bias[col];
#pragma unroll
        for (int r = 0; r < 4; r++) {
          int row = m0 + wr * 64 + mi * 16 + quad * 4 + r;
          Cf[(size_t)row * N + col] = acc[mi][ni][r] + bv;
        }
      }
    }
  }
}

// ---------------- flash attention: 2 bands/wave, balanced segments, XCD-local ----------------
// Block (bh, a): seg0 = tiles (2a, 2a+1), seg1 = tiles (30-2a, 31-2a).
// Max iters/block = (2a+2)+(32-2a) = 34 uniform -> zero tail; 512 blocks all
// co-resident at 2 blocks/CU. grid(64,8): linear%8 = bh%8 -> one bh per XCD L2.
// Round-2: 2-deep register pipeline on K (T14), V issued at compute-top
// (self-hidden under QK+softmax), setprio(1) around MFMA clusters (T5, m191).
__launch_bounds__(256, 2)
__global__ void attn(const __hip_bfloat16* __restrict__ qkv,
                     const __hip_bfloat16* __restrict__ kpack,
                     const __hip_bfloat16* __restrict__ vpack,
                     __hip_bfloat16* __restrict__ obuf) {
  const int tid = threadIdx.x;
  const int w = tid >> 6, lane = tid & 63;
  const int lq = lane & 15, quad = lane >> 4;

  const int bh = (int)blockIdx.x;            // XCD = bh % 8
  const int a  = (int)blockIdx.y;            // 0..7
  const int b = bh >> 4, h = bh & 15;

  const __hip_bfloat16* kb0 = kpack + ((size_t)bh * NST) * 4096 + lane * 8;
  const __hip_bfloat16* vb0 = vpack + ((size_t)bh * NST) * 4096 + lane * 8;

// load K fragments of s-tile TT into named register set (8 x short8)
#define LOADK(KF, KG, TT) do {                                              \
    const __hip_bfloat16* kb_ = kb0 + (size_t)(TT) * 4096;                  \
    _Pragma("unroll") for (int ni = 0; ni < 4; ni++) {                      \
      KF[ni] = *(const short8*)(kb_ + (size_t)(ni * 2 + 0) * 512);          \
      KG[ni] = *(const short8*)(kb_ + (size_t)(ni * 2 + 1) * 512);          \
    }                                                                       \
  } while (0)

// full tile step: V load (issued first, consumed ~350cy later), QK^T, mask,
// exp2+pack, PV. MFMA clusters wrapped in setprio(1).
#define COMPUTE(KF, KG, TT) do {                                            \
    const __hip_bfloat16* vb_ = vb0 + (size_t)(TT) * 4096;                  \
    short8 vfr[8];                                                          \
    _Pragma("unroll") for (int c = 0; c < 8; c++)                           \
      vfr[c] = *(const short8*)(vb_ + (size_t)c * 512);                     \
    floatx4 Sc[2][4];                                                       \
    __builtin_amdgcn_s_setprio(1);                                          \
    _Pragma("unroll") for (int bi = 0; bi < 2; bi++)                        \
    _Pragma("unroll") for (int ni = 0; ni < 4; ni++) {                      \
      floatx4 c0 = (floatx4){0.f, 0.f, 0.f, 0.f};                           \
      c0 = __builtin_amdgcn_mfma_f32_16x16x32_bf16(KF[ni], qf[bi][0], c0, 0, 0, 0); \
      c0 = __builtin_amdgcn_mfma_f32_16x16x32_bf16(KG[ni], qf[bi][1], c0, 0, 0, 0); \
      Sc[bi][ni] = c0;                                                      \
    }                                                                       \
    __builtin_amdgcn_s_setprio(0);                                          \
    if ((TT) == nIter - 1) {                                                \
      _Pragma("unroll") for (int bi = 0; bi < 2; bi++) {                    \
        int lrow_idx = rbase + bi * 16 + lq;                                \
        _Pragma("unroll") for (int ni = 0; ni < 4; ni++)                    \
        _Pragma("unroll") for (int r = 0; r < 4; r++) {                     \
          int s_loc = ni * 16 + quad * 4 + r;                               \
          if (s_loc > lrow_idx) Sc[bi][ni][r] = -__builtin_inff();          \
        }                                                                   \
      }                                                                     \
    }                                                                       \
    bf16x4 pf[2][4];                                                        \
    _Pragma("unroll") for (int bi = 0; bi < 2; bi++)                        \
    _Pragma("unroll") for (int c = 0; c < 4; c++) {                         \
      __hip_bfloat16 pb[4];                                                 \
      _Pragma("unroll") for (int r = 0; r < 4; r++) {                       \
        float p = __builtin_amdgcn_exp2f(Sc[bi][c][r]);                     \
        lrow[bi] += p;                                                      \
        pb[r] = __float2bfloat16(p);                                        \
      }                                                                     \
      pf[bi][c] = *(bf16x4*)pb;                                             \
    }                                                                       \
    __builtin_amdgcn_s_setprio(1);                                          \
    _Pragma("unroll") for (int m = 0; m < 2; m++)                           \
    _Pragma("unroll") for (int nt = 0; nt < 4; nt++) {                      \
      short8 v8 = vfr[m * 4 + nt];                                          \
      bf16x4 vlo = (bf16x4){v8[0], v8[1], v8[2], v8[3]};                    \
      bf16x4 vhi = (bf16x4){v8[4], v8[5], v8[6], v8[7]};                    \
      _Pragma("unroll") for (int bi = 0; bi < 2; bi++) {                    \
        Oacc[bi][nt] = mfma16(pf[bi][2 * m + 0], vlo, Oacc[bi][nt]);        \
        Oacc[bi][nt] = mfma16(pf[bi][2 * m + 1], vhi, Oacc[bi][nt]);        \
      }                                                                     \
    }                                                                       \
    __builtin_amdgcn_s_setprio(0);                                          \
  } while (0)

#pragma unroll 1
  for (int seg = 0; seg < 2; ++seg) {
    const int tbase = seg ? (NST - 2 - 2 * a) : (2 * a);
    const int qt = tbase + (w >> 1);         // this wave's q-tile
    const int rbase = (w & 1) * 32;          // row base within tile

    // Q fragments for 2 bands: B-operand B[n=lq -> t][k=quad*8+j]
    short8 qf[2][2];
#pragma unroll
    for (int bi = 0; bi < 2; bi++) {
      const __hip_bfloat16* qp =
          qkv + ((size_t)(b * T_ + qt * 64 + rbase + bi * 16 + lq)) * NQKV + h * HD_;
      qf[bi][0] = *(const short8*)(qp + quad * 8);
      qf[bi][1] = *(const short8*)(qp + 32 + quad * 8);
    }

    floatx4 Oacc[2][4];
#pragma unroll
    for (int bi = 0; bi < 2; bi++)
#pragma unroll
      for (int i = 0; i < 4; i++) Oacc[bi][i] = (floatx4){0.f, 0.f, 0.f, 0.f};
    float lrow[2] = {0.f, 0.f};

    const int nIter = qt + 1;                // wave loops to its own diagonal

    // 2-deep software pipeline: K fragments ping-pong between named sets
    short8 kfA[4], kgA[4], kfB[4], kgB[4];
    LOADK(kfA, kgA, 0);
    int it = 0;
#pragma unroll 1
    for (; it + 2 <= nIter; it += 2) {
      LOADK(kfB, kgB, it + 1);               // issue next-tile K early
      COMPUTE(kfA, kgA, it);
      if (it + 2 < nIter) LOADK(kfA, kgA, it + 2);
      COMPUTE(kfB, kgB, it + 1);
    }
    if (it < nIter) COMPUTE(kfA, kgA, it);   // odd-count tail

    // epilogue per band: reduce lrow across quads, normalize, store
#pragma unroll
    for (int bi = 0; bi < 2; bi++) {
      float ps = lrow[bi];
      ps += __shfl_xor(ps, 16);
      ps += __shfl_xor(ps, 32);
      float inv = 1.0f / ps;                    // valid for t = lq in every lane
#pragma unroll
      for (int r = 0; r < 4; r++) {
        float invr = __shfl(inv, quad * 4 + r); // inv for t = quad*4+r
        int t = qt * 64 + rbase + bi * 16 + quad * 4 + r;
#pragma unroll
        for (int nt = 0; nt < 4; nt++)
          obuf[(size_t)(b * T_ + t) * D_ + h * HD_ + nt * 16 + lq] =
              __float2bfloat16(Oacc[bi][nt][r] * invr);
      }
    }
  }
#undef LOADK
#undef COMPUTE
}

// ---------------- launch ----------------

extern "C" void kernel_launch(void* const* d_in, const int* in_sizes, int n_in,
                              void* d_out, int out_size, void* d_ws, size_t ws_size,
                              hipStream_t stream) {
  const float* x  = (const float*)d_in[0];
  const float* Wq = (const float*)d_in[1];
  const float* Wk = (const float*)d_in[2];
  const float* Wv = (const float*)d_in[3];
  const float* Wo = (const float*)d_in[4];
  const float* bo = (const float*)d_in[5];
  float* out = (float*)d_out;

  char* ws = (char*)d_ws;
  __hip_bfloat16* xb    = (__hip_bfloat16*)(ws);                          // 16 MB (dead after QKV gemm)
  __hip_bfloat16* obuf  = (__hip_bfloat16*)(ws);                          // reuses xb's slot
  __hip_bfloat16* wqkv  = (__hip_bfloat16*)(ws + ((size_t)16 << 20));     //  6 MB
  __hip_bfloat16* wob   = (__hip_bfloat16*)(ws + ((size_t)22 << 20));     //  2 MB
  __hip_bfloat16* qkv   = (__hip_bfloat16*)(ws + ((size_t)24 << 20));     // 48 MB
  __hip_bfloat16* kpack = (__hip_bfloat16*)(ws + ((size_t)72 << 20));     // 16 MB
  __hip_bfloat16* vpack = (__hip_bfloat16*)(ws + ((size_t)88 << 20));     // 16 MB

  convert_bf16<<<(MROWS * D_) / 1024, 256, 0, stream>>>(x, xb, MROWS * D_);
  convert_bf16<<<(D_ * D_) / 1024, 256, 0, stream>>>(Wo, wob, D_ * D_);
  transpose_w<<<dim3(16, 48), 256, 0, stream>>>(Wq, Wk, Wv, wqkv);

  // qkv = xb * wqkv^T   (q columns pre-scaled by log2e/8)
  gemm_bt<0><<<dim3(MROWS / 128, NQKV / 128), 256, 0, stream>>>(
      xb, wqkv, qkv, nullptr, nullptr, MROWS, NQKV, D_, QSCALE);

  repack_kv<<<dim3(NST, B_ * H_), 256, 0, stream>>>(qkv, kpack, vpack);

  attn<<<dim3(B_ * H_, 8), 256, 0, stream>>>(qkv, kpack, vpack, obuf);

  // out = obuf * Wo^T + bo
  gemm_bt<1><<<dim3(MROWS / 128, D_ / 128), 256, 0, stream>>>(
      obuf, wob, nullptr, out, bo, MROWS, D_, D_, 1.0f);
}

// Round 3
// 248.698 us; speedup vs baseline: 1.0360x; 1.0096x over previous
//
#include <hip/hip_runtime.h>
#include <hip/hip_bf16.h>
#include <stdint.h>

#define B_   4
#define T_   2048
#define D_   1024
#define H_   16
#define HD_  64
#define MROWS (B_*T_)      // 8192
#define NQKV  3072
#define NST  (T_/64)       // 32 s-tiles per head

typedef __attribute__((ext_vector_type(8))) short  short8;   // 8 x bf16
typedef __attribute__((ext_vector_type(4))) short  bf16x4;   // 4 x bf16 (avoid HIP's short4)
typedef __attribute__((ext_vector_type(4))) float  floatx4;

#define QSCALE 0.1803368801111244f   // log2(e)/sqrt(64)

__device__ inline void async_copy16(const __hip_bfloat16* g, __hip_bfloat16* l) {
  __builtin_amdgcn_global_load_lds(
      (const __attribute__((address_space(1))) void*)g,
      (__attribute__((address_space(3))) void*)l, 16, 0, 0);
}

// K=16 bf16 MFMA (gfx950: ..._16x16x16bf16_1k; fallback keeps it compiling)
__device__ inline floatx4 mfma16(bf16x4 a, bf16x4 b, floatx4 c) {
#if __has_builtin(__builtin_amdgcn_mfma_f32_16x16x16bf16_1k)
  return __builtin_amdgcn_mfma_f32_16x16x16bf16_1k(a, b, c, 0, 0, 0);
#elif __has_builtin(__builtin_amdgcn_mfma_f32_16x16x16_bf16)
  return __builtin_amdgcn_mfma_f32_16x16x16_bf16(a, b, c, 0, 0, 0);
#else
  short8 a8 = (short8){a[0], a[1], a[2], a[3], 0, 0, 0, 0};
  short8 b8 = (short8){b[0], b[1], b[2], b[3], 0, 0, 0, 0};
  return __builtin_amdgcn_mfma_f32_16x16x32_bf16(a8, b8, c, 0, 0, 0);
#endif
}

// ---------------- fused prep: convert x, convert Wo, transpose W{q,k,v} ----------------
// blocks [0,8192): x -> bf16 ; [8192,9216): Wo -> bf16 ; [9216,9984): transpose_w
__global__ void prep(const float* __restrict__ x, const float* __restrict__ Wo,
                     const float* __restrict__ Wq, const float* __restrict__ Wk,
                     const float* __restrict__ Wv,
                     __hip_bfloat16* __restrict__ xb, __hip_bfloat16* __restrict__ wob,
                     __hip_bfloat16* __restrict__ wqkv) {
  __shared__ __hip_bfloat16 tile[64][65];
  const int bid = (int)blockIdx.x;
  const int t = threadIdx.x;
  if (bid < 8192) {                      // convert x (8.39M elems)
    int i = (bid * 256 + t) * 4;
    float4 v = *(const float4*)(x + i);
    xb[i + 0] = __float2bfloat16(v.x);
    xb[i + 1] = __float2bfloat16(v.y);
    xb[i + 2] = __float2bfloat16(v.z);
    xb[i + 3] = __float2bfloat16(v.w);
  } else if (bid < 9216) {               // convert Wo (1.05M elems)
    int i = ((bid - 8192) * 256 + t) * 4;
    float4 v = *(const float4*)(Wo + i);
    wob[i + 0] = __float2bfloat16(v.x);
    wob[i + 1] = __float2bfloat16(v.y);
    wob[i + 2] = __float2bfloat16(v.z);
    wob[i + 3] = __float2bfloat16(v.w);
  } else {                               // transpose W
    int idx = bid - 9216;
    const int d0 = (idx & 15) * 64;
    const int wh = idx >> 4;             // 0..47
    const int which = wh >> 4, h = wh & 15;
    const float* W = (which == 0) ? Wq : ((which == 1) ? Wk : Wv);
    const float* base = W + (size_t)h * D_ * HD_;
#pragma unroll
    for (int i = 0; i < 16; i++) {
      int e = i * 256 + t;
      int dr = e >> 6, hd = e & 63;
      tile[dr][hd] = __float2bfloat16(base[(size_t)(d0 + dr) * HD_ + hd]);
    }
    __syncthreads();
#pragma unroll
    for (int i = 0; i < 16; i++) {
      int e = i * 256 + t;
      int hd = e >> 6, dr = e & 63;
      wqkv[(size_t)(which * 1024 + h * 64 + hd) * D_ + d0 + dr] = tile[dr][hd];
    }
  }
}

// ---------------- repack K,V into fragment-contiguous tiles ----------------
__global__ void repack_kv(const __hip_bfloat16* __restrict__ qkv,
                          __hip_bfloat16* __restrict__ kpack, __hip_bfloat16* __restrict__ vpack) {
  __shared__ __hip_bfloat16 Ks[64][72];
  __shared__ __hip_bfloat16 Vs[64][72];
  const int tid = threadIdx.x;
  const int st = blockIdx.x, bh = blockIdx.y;
  const int b = bh >> 4, h = bh & 15;
#pragma unroll
  for (int p = 0; p < 2; p++) {
    int c = p * 256 + tid;           // 512 chunks of 16B per matrix
    int row = c >> 3, col8 = c & 7;
    const __hip_bfloat16* src = qkv + (size_t)(b * T_ + st * 64 + row) * NQKV + h * HD_ + col8 * 8;
    *(uint4*)&Ks[row][col8 * 8] = *(const uint4*)(src + 1024);
    *(uint4*)&Vs[row][col8 * 8] = *(const uint4*)(src + 2048);
  }
  __syncthreads();
  const size_t base = ((size_t)bh * NST + st) * 8 * 512;
#pragma unroll
  for (int p = 0; p < 2; p++) {
    int pair = p * 256 + tid;        // 8 chunks x 64 lanes
    int c = pair >> 6, l = pair & 63;
    int lq = l & 15, q = l >> 4;
    int ni = c >> 1, half = c & 1;
    short8 v = *(const short8*)&Ks[ni * 16 + lq][half * 32 + q * 8];
    *(short8*)(kpack + base + (size_t)c * 512 + l * 8) = v;
  }
#pragma unroll
  for (int p = 0; p < 2; p++) {
    int pair = p * 256 + tid;
    int c = pair >> 6, l = pair & 63;
    int lq = l & 15, q = l >> 4;
    int m = c >> 2, nt = c & 3;
    __hip_bfloat16 tmp[8];
#pragma unroll
    for (int half = 0; half < 2; half++)
#pragma unroll
      for (int j = 0; j < 4; j++)
        tmp[half * 4 + j] = Vs[(2 * m + half) * 16 + q * 4 + j][nt * 16 + lq];
    *(short8*)(vpack + base + (size_t)c * 512 + l * 8) = *(short8*)tmp;
  }
}

// ---------------- GEMM: C = A[M,K] * Bt[N,K]^T ----------------
template <int EPI>
__launch_bounds__(256, 2)
__global__ void gemm_bt(const __hip_bfloat16* __restrict__ A, const __hip_bfloat16* __restrict__ Bt,
                        __hip_bfloat16* __restrict__ Cb, float* __restrict__ Cf,
                        const float* __restrict__ bias, int M, int N, int K, float qscale) {
  __shared__ __hip_bfloat16 As[128 * 32];
  __shared__ __hip_bfloat16 Bs[128 * 32];
  const int tid = threadIdx.x;
  const int w = tid >> 6, lane = tid & 63;
  const int lq = lane & 15, quad = lane >> 4;
  const int wr = w >> 1, wc = w & 1;
  const int m0 = blockIdx.x * 128, n0 = blockIdx.y * 128;

  floatx4 acc[4][4];
#pragma unroll
  for (int i = 0; i < 4; i++)
#pragma unroll
    for (int j = 0; j < 4; j++) acc[i][j] = (floatx4){0.f, 0.f, 0.f, 0.f};

  for (int k0 = 0; k0 < K; k0 += 32) {
    __syncthreads();
#pragma unroll
    for (int ph = 0; ph < 2; ++ph) {
      int c = ph * 256 + tid;
      int row = c >> 2, col8 = c & 3;
      async_copy16(A + (size_t)(m0 + row) * K + k0 + col8 * 8, As + c * 8);
      async_copy16(Bt + (size_t)(n0 + row) * K + k0 + col8 * 8, Bs + c * 8);
    }
    __syncthreads();
    short8 af[4], bf[4];
#pragma unroll
    for (int mi = 0; mi < 4; mi++)
      af[mi] = *(const short8*)(As + (wr * 64 + mi * 16 + lq) * 32 + quad * 8);
#pragma unroll
    for (int ni = 0; ni < 4; ni++)
      bf[ni] = *(const short8*)(Bs + (wc * 64 + ni * 16 + lq) * 32 + quad * 8);
#pragma unroll
    for (int mi = 0; mi < 4; mi++)
#pragma unroll
      for (int ni = 0; ni < 4; ni++)
        acc[mi][ni] = __builtin_amdgcn_mfma_f32_16x16x32_bf16(af[mi], bf[ni], acc[mi][ni], 0, 0, 0);
  }

#pragma unroll
  for (int mi = 0; mi < 4; mi++) {
#pragma unroll
    for (int ni = 0; ni < 4; ni++) {
      int col = n0 + wc * 64 + ni * 16 + lq;
      if (EPI == 0) {
        float s = (col < 1024) ? qscale : 1.0f;
#pragma unroll
        for (int r = 0; r < 4; r++) {
          int row = m0 + wr * 64 + mi * 16 + quad * 4 + r;
          Cb[(size_t)row * N + col] = __float2bfloat16(acc[mi][ni][r] * s);
        }
      } else {
        float bv = bias[col];
#pragma unroll
        for (int r = 0; r < 4; r++) {
          int row = m0 + wr * 64 + mi * 16 + quad * 4 + r;
          Cf[(size_t)row * N + col] = acc[mi][ni][r] + bv;
        }
      }
    }
  }
}

// ---------------- flash attention: LDS-staged K/V, 2 bands/wave, XCD-local ----------------
// Block (bh, a): seg0 = tiles (2a, 2a+1), seg1 = tiles (30-2a, 31-2a); 34 iters/block.
// Round-3: K/V tiles staged once per block into double-buffered LDS via
// global_load_lds (cuts per-CU L2 read traffic 4x — that was the wall; round-2's
// register pipeline was null because latency wasn't the problem, bandwidth was).
// All 4 waves ds_read the same staged tile; wave-level predication (it <= qt) is
// wave-uniform; barriers are outside the predicate.
__launch_bounds__(256, 2)
__global__ void attn(const __hip_bfloat16* __restrict__ qkv,
                     const __hip_bfloat16* __restrict__ kpack,
                     const __hip_bfloat16* __restrict__ vpack,
                     __hip_bfloat16* __restrict__ obuf) {
  __shared__ __hip_bfloat16 KVs[2][8192];    // [buf][K:0..4095 | V:4096..8191], 32 KB
  const int tid = threadIdx.x;
  const int w = tid >> 6, lane = tid & 63;
  const int lq = lane & 15, quad = lane >> 4;

  const int bh = (int)blockIdx.x;            // XCD = bh % 8
  const int a  = (int)blockIdx.y;            // 0..7
  const int b = bh >> 4, h = bh & 15;

  const __hip_bfloat16* kbase = kpack + ((size_t)bh * NST) * 4096;
  const __hip_bfloat16* vbase = vpack + ((size_t)bh * NST) * 4096;

#pragma unroll 1
  for (int seg = 0; seg < 2; ++seg) {
    const int tbase = seg ? (NST - 2 - 2 * a) : (2 * a);
    const int qt = tbase + (w >> 1);         // this wave's q-tile
    const int rbase = (w & 1) * 32;          // row base within tile

    // Q fragments for 2 bands: B-operand B[n=lq -> t][k=quad*8+j]
    short8 qf[2][2];
#pragma unroll
    for (int bi = 0; bi < 2; bi++) {
      const __hip_bfloat16* qp =
          qkv + ((size_t)(b * T_ + qt * 64 + rbase + bi * 16 + lq)) * NQKV + h * HD_;
      qf[bi][0] = *(const short8*)(qp + quad * 8);
      qf[bi][1] = *(const short8*)(qp + 32 + quad * 8);
    }

    floatx4 Oacc[2][4];
#pragma unroll
    for (int bi = 0; bi < 2; bi++)
#pragma unroll
      for (int i = 0; i < 4; i++) Oacc[bi][i] = (floatx4){0.f, 0.f, 0.f, 0.f};
    float lrow[2] = {0.f, 0.f};

    const int itTop = tbase + 1;             // block iterates tiles 0..itTop

    // stage tile 0 into buf 0: 1024 16B-chunks, 4 per thread (lane-contiguous)
#pragma unroll
    for (int j = 0; j < 2; ++j) {
      int c = j * 256 + tid;
      async_copy16(kbase + (size_t)c * 8, &KVs[0][0] + c * 8);
      async_copy16(vbase + (size_t)c * 8, &KVs[0][4096] + c * 8);
    }
    __syncthreads();

#pragma unroll 1
    for (int it = 0; it <= itTop; ++it) {
      const int cur = it & 1;
      if (it < itTop) {                      // stage next tile into other buffer
        const __hip_bfloat16* kn = kbase + (size_t)(it + 1) * 4096;
        const __hip_bfloat16* vn = vbase + (size_t)(it + 1) * 4096;
#pragma unroll
        for (int j = 0; j < 2; ++j) {
          int c = j * 256 + tid;
          async_copy16(kn + (size_t)c * 8, &KVs[cur ^ 1][0] + c * 8);
          async_copy16(vn + (size_t)c * 8, &KVs[cur ^ 1][4096] + c * 8);
        }
      }
      if (it <= qt) {                        // wave-uniform predicate
        const __hip_bfloat16* Kb = &KVs[cur][0] + lane * 8;
        const __hip_bfloat16* Vb = &KVs[cur][4096] + lane * 8;
        short8 kf[4], kg[4];
#pragma unroll
        for (int ni = 0; ni < 4; ni++) {
          kf[ni] = *(const short8*)(Kb + (size_t)(ni * 2 + 0) * 512);
          kg[ni] = *(const short8*)(Kb + (size_t)(ni * 2 + 1) * 512);
        }
        short8 vfr[8];
#pragma unroll
        for (int c = 0; c < 8; c++) vfr[c] = *(const short8*)(Vb + (size_t)c * 512);

        // S^T = K Q^T for both bands (exp2 domain)
        floatx4 Sc[2][4];
        __builtin_amdgcn_s_setprio(1);
#pragma unroll
        for (int bi = 0; bi < 2; bi++)
#pragma unroll
          for (int ni = 0; ni < 4; ni++) {
            floatx4 c0 = (floatx4){0.f, 0.f, 0.f, 0.f};
            c0 = __builtin_amdgcn_mfma_f32_16x16x32_bf16(kf[ni], qf[bi][0], c0, 0, 0, 0);
            c0 = __builtin_amdgcn_mfma_f32_16x16x32_bf16(kg[ni], qf[bi][1], c0, 0, 0, 0);
            Sc[bi][ni] = c0;   // reg r: s = ni*16 + quad*4 + r, t = lq (band bi)
          }
        __builtin_amdgcn_s_setprio(0);

        // causal mask on the wave's diagonal tile
        if (it == qt) {
#pragma unroll
          for (int bi = 0; bi < 2; bi++) {
            int lrow_idx = rbase + bi * 16 + lq;
#pragma unroll
            for (int ni = 0; ni < 4; ni++)
#pragma unroll
              for (int r = 0; r < 4; r++) {
                int s_loc = ni * 16 + quad * 4 + r;
                if (s_loc > lrow_idx) Sc[bi][ni][r] = -__builtin_inff();
              }
          }
        }

        // p = exp2(S); per-lane row sums; pack to PV A-frags
        bf16x4 pf[2][4];
#pragma unroll
        for (int bi = 0; bi < 2; bi++)
#pragma unroll
          for (int c = 0; c < 4; c++) {
            __hip_bfloat16 pb[4];
#pragma unroll
            for (int r = 0; r < 4; r++) {
              float p = __builtin_amdgcn_exp2f(Sc[bi][c][r]);
              lrow[bi] += p;
              pb[r] = __float2bfloat16(p);
            }
            pf[bi][c] = *(bf16x4*)pb;
          }

        // O += P V  (both bands share the V fragments)
        __builtin_amdgcn_s_setprio(1);
#pragma unroll
        for (int m = 0; m < 2; m++)
#pragma unroll
          for (int nt = 0; nt < 4; nt++) {
            short8 v8 = vfr[m * 4 + nt];
            bf16x4 vlo = (bf16x4){v8[0], v8[1], v8[2], v8[3]};
            bf16x4 vhi = (bf16x4){v8[4], v8[5], v8[6], v8[7]};
#pragma unroll
            for (int bi = 0; bi < 2; bi++) {
              Oacc[bi][nt] = mfma16(pf[bi][2 * m + 0], vlo, Oacc[bi][nt]);
              Oacc[bi][nt] = mfma16(pf[bi][2 * m + 1], vhi, Oacc[bi][nt]);
            }
          }
        __builtin_amdgcn_s_setprio(0);
      }
      __syncthreads();                       // drains staging vmcnt; buffers flip
    }

    // epilogue per band: reduce lrow across quads, normalize, store
#pragma unroll
    for (int bi = 0; bi < 2; bi++) {
      float ps = lrow[bi];
      ps += __shfl_xor(ps, 16);
      ps += __shfl_xor(ps, 32);
      float inv = 1.0f / ps;                    // valid for t = lq in every lane
#pragma unroll
      for (int r = 0; r < 4; r++) {
        float invr = __shfl(inv, quad * 4 + r); // inv for t = quad*4+r
        int t = qt * 64 + rbase + bi * 16 + quad * 4 + r;
#pragma unroll
        for (int nt = 0; nt < 4; nt++)
          obuf[(size_t)(b * T_ + t) * D_ + h * HD_ + nt * 16 + lq] =
              __float2bfloat16(Oacc[bi][nt][r] * invr);
      }
    }
  }
}

// ---------------- launch ----------------

extern "C" void kernel_launch(void* const* d_in, const int* in_sizes, int n_in,
                              void* d_out, int out_size, void* d_ws, size_t ws_size,
                              hipStream_t stream) {
  const float* x  = (const float*)d_in[0];
  const float* Wq = (const float*)d_in[1];
  const float* Wk = (const float*)d_in[2];
  const float* Wv = (const float*)d_in[3];
  const float* Wo = (const float*)d_in[4];
  const float* bo = (const float*)d_in[5];
  float* out = (float*)d_out;

  char* ws = (char*)d_ws;
  __hip_bfloat16* xb    = (__hip_bfloat16*)(ws);                          // 16 MB (dead after QKV gemm)
  __hip_bfloat16* obuf  = (__hip_bfloat16*)(ws);                          // reuses xb's slot
  __hip_bfloat16* wqkv  = (__hip_bfloat16*)(ws + ((size_t)16 << 20));     //  6 MB
  __hip_bfloat16* wob   = (__hip_bfloat16*)(ws + ((size_t)22 << 20));     //  2 MB
  __hip_bfloat16* qkv   = (__hip_bfloat16*)(ws + ((size_t)24 << 20));     // 48 MB
  __hip_bfloat16* kpack = (__hip_bfloat16*)(ws + ((size_t)72 << 20));     // 16 MB
  __hip_bfloat16* vpack = (__hip_bfloat16*)(ws + ((size_t)88 << 20));     // 16 MB

  prep<<<9984, 256, 0, stream>>>(x, Wo, Wq, Wk, Wv, xb, wob, wqkv);

  // qkv = xb * wqkv^T   (q columns pre-scaled by log2e/8)
  gemm_bt<0><<<dim3(MROWS / 128, NQKV / 128), 256, 0, stream>>>(
      xb, wqkv, qkv, nullptr, nullptr, MROWS, NQKV, D_, QSCALE);

  repack_kv<<<dim3(NST, B_ * H_), 256, 0, stream>>>(qkv, kpack, vpack);

  attn<<<dim3(B_ * H_, 8), 256, 0, stream>>>(qkv, kpack, vpack, obuf);

  // out = obuf * Wo^T + bo
  gemm_bt<1><<<dim3(MROWS / 128, D_ / 128), 256, 0, stream>>>(
      obuf, wob, nullptr, out, bo, MROWS, D_, D_, 1.0f);
}